// Round 1
// baseline (503.985 us; speedup 1.0000x reference)
//
#include <hip/hip_runtime.h>
#include <math.h>

#define N_NODES 100000
#define N_EDGES 800000
#define F 128
#define NBUCK ((N_NODES + 255) / 256)   // 391 buckets of 256 target nodes
#define SCAP 3072                       // staged edges per bucket (mean 2046, +22 sigma)
#define BSPAN 4096                      // padded CSR span per bucket (mean 2944, +16 sigma)

typedef __attribute__((ext_vector_type(8))) short short8;
typedef __attribute__((ext_vector_type(4))) float floatx4;

__device__ __forceinline__ unsigned short f2bf(float f) {
    unsigned u = __float_as_uint(f);
    u += 0x7fffu + ((u >> 16) & 1u);          // round-to-nearest-even
    return (unsigned short)(u >> 16);
}
__device__ __forceinline__ float bf_lo(unsigned u) { return __uint_as_float(u << 16); }
__device__ __forceinline__ float bf_hi(unsigned u) { return __uint_as_float(u & 0xffff0000u); }
__device__ __forceinline__ unsigned pack2(float a, float b) {
    return (unsigned)f2bf(a) | ((unsigned)f2bf(b) << 16);
}

// ---------------- CSR build: bucketed counting sort ----------------
// Pass 1: stage edges per 256-node bucket. The bucket cursor's atomicAdd makes
// the 4B stores temporally sequential per bucket -> lines fill completely in L2,
// no write amplification (old k_fill: 55 MB written for 3.2 MB payload).

__global__ void k_fill2(const int* __restrict__ row, const int* __restrict__ col,
                        int* __restrict__ bcnt, unsigned* __restrict__ stage) {
    int e = blockIdx.x * blockDim.x + threadIdx.x;
    if (e >= N_EDGES) return;
    int r = row[e], c = col[e];
    int bk = c >> 8;
    int p = atomicAdd(&bcnt[bk], 1);
    if (p < SCAP)                                  // cannot trigger (+22 sigma); guards OOB
        stage[(size_t)bk * SCAP + p] = ((unsigned)(c & 255) << 20) | (unsigned)(r + 1);
}

// Pass 2: one block per bucket. LDS histogram -> LDS scan of 8-padded counts ->
// LDS scatter -> coalesced flush. Also emits rp2 (start,end), dinv, dinv2, so the
// global scan kernels and per-node histogram kernel are gone entirely.

__global__ __launch_bounds__(256) void k_build(const int* __restrict__ bcnt,
                                               const unsigned* __restrict__ stage,
                                               unsigned* __restrict__ csr,
                                               int2* __restrict__ rp2,
                                               float* __restrict__ dinv,
                                               float* __restrict__ dinv2) {
    __shared__ int hist[256];
    __shared__ int sc[256];
    __shared__ int cursor[256];
    __shared__ int spanTot;
    __shared__ unsigned img[BSPAN];                // 16 KB bucket-local CSR image
    int bk = blockIdx.x, t = threadIdx.x;
    int n = bcnt[bk]; n = n < SCAP ? n : SCAP;
    hist[t] = 0;
    __syncthreads();
    const unsigned* sp = stage + (size_t)bk * SCAP;
    for (int i = t; i < n; i += 256) atomicAdd(&hist[sp[i] >> 20], 1);
    __syncthreads();
    int cdeg = hist[t];
    int pad = (cdeg + 7) & ~7;                     // rows 8-padded (hop loads uint4 pairs)
    sc[t] = pad;
    __syncthreads();
#pragma unroll
    for (int off = 1; off < 256; off <<= 1) {      // Hillis-Steele inclusive scan
        int u = (t >= off) ? sc[t - off] : 0;
        __syncthreads();
        sc[t] += u;
        __syncthreads();
    }
    int excl = sc[t] - pad;
    if (t == 255) spanTot = sc[255];
    cursor[t] = excl;
    __syncthreads();
    int tot = spanTot;
    int node = bk * 256 + t;
    if (node < N_NODES) {
        int base = bk * BSPAN;
        rp2[node] = (int2){base + excl, base + excl + pad};
        float d = rsqrtf((float)cdeg + 1.0f);      // +1 self-loop
        dinv[node] = d; dinv2[node] = d * d;
    }
    for (int i = t; i < tot; i += 256) img[i] = 0u;   // pad slots -> zero row
    __syncthreads();
    for (int i = t; i < n; i += 256) {
        unsigned v = sp[i];
        int pos = atomicAdd(&cursor[v >> 20], 1);
        img[pos] = v & 0xFFFFFu;                   // r+1 (rows shifted +1)
    }
    __syncthreads();
    unsigned* op = csr + (size_t)bk * BSPAN;
    for (int i = t; i < tot; i += 256) op[i] = img[i];   // coalesced flush
}

// prep: xb[(v+1)] = bf16(dinv[v] * x[v])  (shifted rows; row 0 = zeros).
// Also zeroes row 0 of h1b. Runs after k_build (needs dinv; also stage aliases h1b).
__global__ void k_prep(const float4* __restrict__ x, const float* __restrict__ dinv,
                       uint2* __restrict__ xb, uint2* __restrict__ h1b) {
    int i = blockIdx.x * blockDim.x + threadIdx.x;
    if (i < 32) { xb[i] = (uint2){0u, 0u}; h1b[i] = (uint2){0u, 0u}; }
    if (i >= N_NODES * 32) return;
    int node = i >> 5;
    float d = dinv[node];
    float4 v = x[i];
    uint2 o; o.x = pack2(d * v.x, d * v.y); o.y = pack2(d * v.z, d * v.w);
    xb[i + 32] = o;                            // row node+1
}

// ---------------- propagation: weight-free gather, 2 nodes/wave, exact 8-deep ----------------
// acc = y[c] + sum y[r]; out = scale[c] * acc  (scale = dinv^2 for hop1 -> y1,
// dinv for hop2 -> h2). Rows shifted +1; pad entries hit zero row 0 (L1-hot).

__global__ __launch_bounds__(256) void k_hop(const int2* __restrict__ rp2,
                                             const unsigned* __restrict__ csr,
                                             const float* __restrict__ scale,
                                             const uint2* __restrict__ src,
                                             uint2* __restrict__ dst) {
    int wv = (blockIdx.x * blockDim.x + threadIdx.x) >> 6;
    int lane = threadIdx.x & 63;
    int half = lane >> 5, off = lane & 31;
    int node = wv * 2 + half;                       // 50k waves exact
    if (node >= N_NODES) return;
    uint2 u = src[(size_t)(node + 1) * 32 + off];   // own (pre-scaled) row
    float a0 = bf_lo(u.x), a1 = bf_hi(u.x);
    float a2 = bf_lo(u.y), a3 = bf_hi(u.y);
    int2 rp = rp2[node];
    int e = rp.x, end = rp.y;                       // end-e is a multiple of 8
    for (; e < end; e += 8) {
        const uint4* cp = (const uint4*)(csr + e);  // 16B-aligned (8-padded rows)
        uint4 c0 = cp[0], c1 = cp[1];               // 8 indices, broadcast loads
        unsigned idx[8] = {c0.x, c0.y, c0.z, c0.w, c1.x, c1.y, c1.z, c1.w};
#pragma unroll
        for (int j = 0; j < 8; ++j) {
            uint2 v = src[(size_t)idx[j] * 32 + off];
            a0 += bf_lo(v.x); a1 += bf_hi(v.x);
            a2 += bf_lo(v.y); a3 += bf_hi(v.y);
        }
    }
    float s = scale[node];
    uint2 o; o.x = pack2(s * a0, s * a1); o.y = pack2(s * a2, s * a3);
    dst[(size_t)(node + 1) * 32 + off] = o;
}

// ---------------- MFMA GEMM + bias + log_softmax ----------------

__global__ __launch_bounds__(256) void k_gemm_lsm_mfma(const unsigned short* __restrict__ h,
                                                       const float* __restrict__ W,
                                                       const float* __restrict__ b,
                                                       float* __restrict__ out) {
    int lane = threadIdx.x & 63;
    int wave = threadIdx.x >> 6;
    int m = lane & 15, quad = lane >> 4;

    // B fragment: lane holds B[k=quad*8+j][n=m] = W[16t+m][ks*32+quad*8+j]
    short8 bfr[8][4];
    float bv[8];
#pragma unroll
    for (int t = 0; t < 8; ++t) {
        bv[t] = b[16 * t + m];
        const float* wr = W + (size_t)(16 * t + m) * 128;
#pragma unroll
        for (int ks = 0; ks < 4; ++ks) {
            const float* wp = wr + ks * 32 + quad * 8;
            short8 v;
#pragma unroll
            for (int j = 0; j < 8; ++j) v[j] = (short)f2bf(wp[j]);
            bfr[t][ks] = v;
        }
    }

    const int ngroups = (N_NODES + 63) / 64;        // 1563 groups of 64 nodes
    for (int g = blockIdx.x; g < ngroups; g += gridDim.x) {
        int gbase = g * 64 + wave * 16;
        int nodeA = gbase + m;
        int node_c = nodeA < N_NODES ? nodeA : N_NODES - 1;
        short8 a[4];
#pragma unroll
        for (int ks = 0; ks < 4; ++ks)
            a[ks] = *(const short8*)(h + (size_t)node_c * 128 + ks * 32 + quad * 8);
        floatx4 acc[8];
#pragma unroll
        for (int t = 0; t < 8; ++t) acc[t] = (floatx4){bv[t], bv[t], bv[t], bv[t]};
#pragma unroll
        for (int ks = 0; ks < 4; ++ks)
#pragma unroll
            for (int t = 0; t < 8; ++t)
                acc[t] = __builtin_amdgcn_mfma_f32_16x16x32_bf16(a[ks], bfr[t][ks], acc[t], 0, 0, 0);

        // D layout: row = gbase + quad*4 + r, col = 16t + m
#pragma unroll
        for (int r = 0; r < 4; ++r) {
            float mx = acc[0][r];
#pragma unroll
            for (int t = 1; t < 8; ++t) mx = fmaxf(mx, acc[t][r]);
#pragma unroll
            for (int msk = 1; msk < 16; msk <<= 1) mx = fmaxf(mx, __shfl_xor(mx, msk));
            float sm = 0.f;
#pragma unroll
            for (int t = 0; t < 8; ++t) sm += __expf(acc[t][r] - mx);
#pragma unroll
            for (int msk = 1; msk < 16; msk <<= 1) sm += __shfl_xor(sm, msk);
            float l = mx + __logf(sm);
            int rown = gbase + quad * 4 + r;
            if (rown < N_NODES) {
                float* op = out + (size_t)rown * 128 + m;
#pragma unroll
                for (int t = 0; t < 8; ++t) op[16 * t] = acc[t][r] - l;
            }
        }
    }
}

// ---------------- launch ----------------

extern "C" void kernel_launch(void* const* d_in, const int* in_sizes, int n_in,
                              void* d_out, int out_size, void* d_ws, size_t ws_size,
                              hipStream_t stream) {
    const float* x = (const float*)d_in[0];
    const float* W = (const float*)d_in[1];
    const float* b = (const float*)d_in[2];
    const int* edge = (const int*)d_in[3];
    const int* row = edge;             // source nodes j
    const int* col = edge + N_EDGES;   // target nodes i
    float* out = (float*)d_out;

    // workspace layout (4B word offsets)
    int*      bcnt  = (int*)d_ws;                     // 391 (padded 1024) - only memset
    float*    dinv  = (float*)(bcnt + 1024);          // 100k
    float*    dinv2 = dinv + 102400;                  // 100k
    int2*     rp2   = (int2*)(dinv2 + 102400);        // 100k (start,end)
    unsigned* csr   = (unsigned*)(rp2 + 102400);      // NBUCK*BSPAN = 1.6M (6.4 MB)
    uint2*    xb    = (uint2*)(csr + (size_t)NBUCK * BSPAN);  // (N+1)*32 uint2 = 25.6 MB
    uint2*    h1b   = xb + 32 * (N_NODES + 1);        // (N+1)*32 uint2
    uint2*    h2b   = xb;                             // reuse: xb dead after hop 1
    // stage aliases h1b past its zero-row (h1b is only written by k_hop #1,
    // which launches after k_build has consumed stage; stream order serializes).
    unsigned* stage = (unsigned*)(h1b + 32);          // NBUCK*SCAP = 4.8 MB

    int nb_edges = (N_EDGES + 255) / 256;
    int nb_prep = (N_NODES * 32 + 255) / 256;         // 12500

    hipMemsetAsync(bcnt, 0, 1024 * 4, stream);        // 4 KB (was 6.4 MB)
    k_fill2<<<nb_edges, 256, 0, stream>>>(row, col, bcnt, stage);
    k_build<<<NBUCK, 256, 0, stream>>>(bcnt, stage, csr, rp2, dinv, dinv2);
    k_prep<<<nb_prep, 256, 0, stream>>>((const float4*)x, dinv, xb, h1b);

    int hop_blocks = (N_NODES / 2 * 64) / 256;        // 12500: one wave per 2 nodes
    k_hop<<<hop_blocks, 256, 0, stream>>>(rp2, csr, dinv2, xb, h1b);   // -> y1
    k_hop<<<hop_blocks, 256, 0, stream>>>(rp2, csr, dinv, h1b, h2b);   // -> h2

    k_gemm_lsm_mfma<<<512, 256, 0, stream>>>((const unsigned short*)(h2b + 32), W, b, out);
}

// Round 2
// 261.469 us; speedup vs baseline: 1.9275x; 1.9275x over previous
//
#include <hip/hip_runtime.h>
#include <math.h>

#define N_NODES 100000
#define N_EDGES 800000
#define F 128
#define NBUCK ((N_NODES + 255) / 256)   // 391 buckets of 256 target nodes
#define NREP 8                          // counter/stage replicas (~1 per XCD)
#define SCAP_R 512                      // staged edges per (bucket,replica): mean 256, +16 sigma
#define CPAD 32                         // counter stride in ints = 128B = own L2 line
#define BSPAN 4096                      // padded CSR span per bucket (mean 2944, +16 sigma)

typedef __attribute__((ext_vector_type(8))) short short8;
typedef __attribute__((ext_vector_type(4))) float floatx4;

__device__ __forceinline__ unsigned short f2bf(float f) {
    unsigned u = __float_as_uint(f);
    u += 0x7fffu + ((u >> 16) & 1u);          // round-to-nearest-even
    return (unsigned short)(u >> 16);
}
__device__ __forceinline__ float bf_lo(unsigned u) { return __uint_as_float(u << 16); }
__device__ __forceinline__ float bf_hi(unsigned u) { return __uint_as_float(u & 0xffff0000u); }
__device__ __forceinline__ unsigned pack2(float a, float b) {
    return (unsigned)f2bf(a) | ((unsigned)f2bf(b) << 16);
}

// ---------------- CSR build: bucketed counting sort, contention-free counters ----------
// Atomics serialize per cache LINE at the coherence point (round-1 lesson: 391
// packed counters = 25 lines = 32k serial ops/line = 282us). Fix: each counter
// gets its own 128B line (CPAD) and is 8-way replicated by blockIdx&7 (~XCD id
// under round-robin dispatch) -> ~256 ops/line, and each replica's stage segment
// is filled from one XCD -> lines fill completely in that L2, no write bounce.

__global__ void k_fill2(const int* __restrict__ row, const int* __restrict__ col,
                        int* __restrict__ bcnt, unsigned* __restrict__ stage) {
    int e = blockIdx.x * blockDim.x + threadIdx.x;
    if (e >= N_EDGES) return;
    int r = row[e], c = col[e];
    int bk = c >> 8;
    int ctr = (bk << 3) | (blockIdx.x & (NREP - 1));
    int p = atomicAdd(&bcnt[ctr * CPAD], 1);
    if (p < SCAP_R)                                // cannot trigger (+16 sigma); guards OOB
        stage[(size_t)ctr * SCAP_R + p] = ((unsigned)(c & 255) << 20) | (unsigned)(r + 1);
}

// Pass 2: one block per bucket. Drain 8 replica segments: LDS histogram -> LDS
// scan of 8-padded counts -> LDS scatter -> coalesced flush. Emits rp2, dinv, dinv2.

__global__ __launch_bounds__(256) void k_build(const int* __restrict__ bcnt,
                                               const unsigned* __restrict__ stage,
                                               unsigned* __restrict__ csr,
                                               int2* __restrict__ rp2,
                                               float* __restrict__ dinv,
                                               float* __restrict__ dinv2) {
    __shared__ int hist[256];
    __shared__ int sc[256];
    __shared__ int cursor[256];
    __shared__ int spanTot;
    __shared__ unsigned img[BSPAN];                // 16 KB bucket-local CSR image
    int bk = blockIdx.x, t = threadIdx.x;
    hist[t] = 0;
    __syncthreads();
#pragma unroll
    for (int rep = 0; rep < NREP; ++rep) {
        int ctr = (bk << 3) | rep;
        int n = bcnt[ctr * CPAD]; n = n < SCAP_R ? n : SCAP_R;
        const unsigned* sp = stage + (size_t)ctr * SCAP_R;
        for (int i = t; i < n; i += 256) atomicAdd(&hist[sp[i] >> 20], 1);
    }
    __syncthreads();
    int cdeg = hist[t];
    int pad = (cdeg + 7) & ~7;                     // rows 8-padded (hop loads uint4 pairs)
    sc[t] = pad;
    __syncthreads();
#pragma unroll
    for (int off = 1; off < 256; off <<= 1) {      // Hillis-Steele inclusive scan
        int u = (t >= off) ? sc[t - off] : 0;
        __syncthreads();
        sc[t] += u;
        __syncthreads();
    }
    int excl = sc[t] - pad;
    if (t == 255) spanTot = sc[255];
    cursor[t] = excl;
    __syncthreads();
    int tot = spanTot;
    int node = bk * 256 + t;
    if (node < N_NODES) {
        int base = bk * BSPAN;
        rp2[node] = (int2){base + excl, base + excl + pad};
        float d = rsqrtf((float)cdeg + 1.0f);      // +1 self-loop
        dinv[node] = d; dinv2[node] = d * d;
    }
    for (int i = t; i < tot; i += 256) img[i] = 0u;   // pad slots -> zero row
    __syncthreads();
#pragma unroll
    for (int rep = 0; rep < NREP; ++rep) {
        int ctr = (bk << 3) | rep;
        int n = bcnt[ctr * CPAD]; n = n < SCAP_R ? n : SCAP_R;
        const unsigned* sp = stage + (size_t)ctr * SCAP_R;
        for (int i = t; i < n; i += 256) {
            unsigned v = sp[i];
            int pos = atomicAdd(&cursor[v >> 20], 1);
            img[pos] = v & 0xFFFFFu;               // r+1 (rows shifted +1)
        }
    }
    __syncthreads();
    unsigned* op = csr + (size_t)bk * BSPAN;
    for (int i = t; i < tot; i += 256) op[i] = img[i];   // coalesced flush
}

// prep: xb[(v+1)] = bf16(dinv[v] * x[v])  (shifted rows; row 0 = zeros).
// Also zeroes row 0 of h1b. Runs after k_build (needs dinv; also stage aliases h1b).
__global__ void k_prep(const float4* __restrict__ x, const float* __restrict__ dinv,
                       uint2* __restrict__ xb, uint2* __restrict__ h1b) {
    int i = blockIdx.x * blockDim.x + threadIdx.x;
    if (i < 32) { xb[i] = (uint2){0u, 0u}; h1b[i] = (uint2){0u, 0u}; }
    if (i >= N_NODES * 32) return;
    int node = i >> 5;
    float d = dinv[node];
    float4 v = x[i];
    uint2 o; o.x = pack2(d * v.x, d * v.y); o.y = pack2(d * v.z, d * v.w);
    xb[i + 32] = o;                            // row node+1
}

// ---------------- propagation: weight-free gather, 2 nodes/wave, exact 8-deep ----------------
// acc = y[c] + sum y[r]; out = scale[c] * acc  (scale = dinv^2 for hop1 -> y1,
// dinv for hop2 -> h2). Rows shifted +1; pad entries hit zero row 0 (L1-hot).

__global__ __launch_bounds__(256) void k_hop(const int2* __restrict__ rp2,
                                             const unsigned* __restrict__ csr,
                                             const float* __restrict__ scale,
                                             const uint2* __restrict__ src,
                                             uint2* __restrict__ dst) {
    int wv = (blockIdx.x * blockDim.x + threadIdx.x) >> 6;
    int lane = threadIdx.x & 63;
    int half = lane >> 5, off = lane & 31;
    int node = wv * 2 + half;                       // 50k waves exact
    if (node >= N_NODES) return;
    uint2 u = src[(size_t)(node + 1) * 32 + off];   // own (pre-scaled) row
    float a0 = bf_lo(u.x), a1 = bf_hi(u.x);
    float a2 = bf_lo(u.y), a3 = bf_hi(u.y);
    int2 rp = rp2[node];
    int e = rp.x, end = rp.y;                       // end-e is a multiple of 8
    for (; e < end; e += 8) {
        const uint4* cp = (const uint4*)(csr + e);  // 16B-aligned (8-padded rows)
        uint4 c0 = cp[0], c1 = cp[1];               // 8 indices, broadcast loads
        unsigned idx[8] = {c0.x, c0.y, c0.z, c0.w, c1.x, c1.y, c1.z, c1.w};
#pragma unroll
        for (int j = 0; j < 8; ++j) {
            uint2 v = src[(size_t)idx[j] * 32 + off];
            a0 += bf_lo(v.x); a1 += bf_hi(v.x);
            a2 += bf_lo(v.y); a3 += bf_hi(v.y);
        }
    }
    float s = scale[node];
    uint2 o; o.x = pack2(s * a0, s * a1); o.y = pack2(s * a2, s * a3);
    dst[(size_t)(node + 1) * 32 + off] = o;
}

// ---------------- MFMA GEMM + bias + log_softmax ----------------

__global__ __launch_bounds__(256) void k_gemm_lsm_mfma(const unsigned short* __restrict__ h,
                                                       const float* __restrict__ W,
                                                       const float* __restrict__ b,
                                                       float* __restrict__ out) {
    int lane = threadIdx.x & 63;
    int wave = threadIdx.x >> 6;
    int m = lane & 15, quad = lane >> 4;

    // B fragment: lane holds B[k=quad*8+j][n=m] = W[16t+m][ks*32+quad*8+j]
    short8 bfr[8][4];
    float bv[8];
#pragma unroll
    for (int t = 0; t < 8; ++t) {
        bv[t] = b[16 * t + m];
        const float* wr = W + (size_t)(16 * t + m) * 128;
#pragma unroll
        for (int ks = 0; ks < 4; ++ks) {
            const float* wp = wr + ks * 32 + quad * 8;
            short8 v;
#pragma unroll
            for (int j = 0; j < 8; ++j) v[j] = (short)f2bf(wp[j]);
            bfr[t][ks] = v;
        }
    }

    const int ngroups = (N_NODES + 63) / 64;        // 1563 groups of 64 nodes
    for (int g = blockIdx.x; g < ngroups; g += gridDim.x) {
        int gbase = g * 64 + wave * 16;
        int nodeA = gbase + m;
        int node_c = nodeA < N_NODES ? nodeA : N_NODES - 1;
        short8 a[4];
#pragma unroll
        for (int ks = 0; ks < 4; ++ks)
            a[ks] = *(const short8*)(h + (size_t)node_c * 128 + ks * 32 + quad * 8);
        floatx4 acc[8];
#pragma unroll
        for (int t = 0; t < 8; ++t) acc[t] = (floatx4){bv[t], bv[t], bv[t], bv[t]};
#pragma unroll
        for (int ks = 0; ks < 4; ++ks)
#pragma unroll
            for (int t = 0; t < 8; ++t)
                acc[t] = __builtin_amdgcn_mfma_f32_16x16x32_bf16(a[ks], bfr[t][ks], acc[t], 0, 0, 0);

        // D layout: row = gbase + quad*4 + r, col = 16t + m
#pragma unroll
        for (int r = 0; r < 4; ++r) {
            float mx = acc[0][r];
#pragma unroll
            for (int t = 1; t < 8; ++t) mx = fmaxf(mx, acc[t][r]);
#pragma unroll
            for (int msk = 1; msk < 16; msk <<= 1) mx = fmaxf(mx, __shfl_xor(mx, msk));
            float sm = 0.f;
#pragma unroll
            for (int t = 0; t < 8; ++t) sm += __expf(acc[t][r] - mx);
#pragma unroll
            for (int msk = 1; msk < 16; msk <<= 1) sm += __shfl_xor(sm, msk);
            float l = mx + __logf(sm);
            int rown = gbase + quad * 4 + r;
            if (rown < N_NODES) {
                float* op = out + (size_t)rown * 128 + m;
#pragma unroll
                for (int t = 0; t < 8; ++t) op[16 * t] = acc[t][r] - l;
            }
        }
    }
}

// ---------------- launch ----------------

extern "C" void kernel_launch(void* const* d_in, const int* in_sizes, int n_in,
                              void* d_out, int out_size, void* d_ws, size_t ws_size,
                              hipStream_t stream) {
    const float* x = (const float*)d_in[0];
    const float* W = (const float*)d_in[1];
    const float* b = (const float*)d_in[2];
    const int* edge = (const int*)d_in[3];
    const int* row = edge;             // source nodes j
    const int* col = edge + N_EDGES;   // target nodes i
    float* out = (float*)d_out;

    // workspace layout (4B word offsets)
    int*      bcnt  = (int*)d_ws;                     // NBUCK*NREP padded ctrs (400KB) - only memset
    float*    dinv  = (float*)(bcnt + NBUCK * NREP * CPAD + 256);
    float*    dinv2 = dinv + 102400;                  // 100k
    int2*     rp2   = (int2*)(dinv2 + 102400);        // 100k (start,end)
    unsigned* csr   = (unsigned*)(rp2 + 102400);      // NBUCK*BSPAN = 1.6M (6.4 MB)
    uint2*    xb    = (uint2*)(csr + (size_t)NBUCK * BSPAN);  // (N+1)*32 uint2 = 25.6 MB
    uint2*    h1b   = xb + 32 * (N_NODES + 1);        // (N+1)*32 uint2
    uint2*    h2b   = xb;                             // reuse: xb dead after hop 1
    // stage aliases h1b past its zero-row (h1b is only written by k_hop #1,
    // which launches after k_build has consumed stage; stream order serializes).
    unsigned* stage = (unsigned*)(h1b + 32);          // NBUCK*NREP*SCAP_R*4 = 6.4 MB

    int nb_edges = (N_EDGES + 255) / 256;
    int nb_prep = (N_NODES * 32 + 255) / 256;         // 12500

    hipMemsetAsync(bcnt, 0, (size_t)NBUCK * NREP * CPAD * 4, stream);  // 400 KB
    k_fill2<<<nb_edges, 256, 0, stream>>>(row, col, bcnt, stage);
    k_build<<<NBUCK, 256, 0, stream>>>(bcnt, stage, csr, rp2, dinv, dinv2);
    k_prep<<<nb_prep, 256, 0, stream>>>((const float4*)x, dinv, xb, h1b);

    int hop_blocks = (N_NODES / 2 * 64) / 256;        // 12500: one wave per 2 nodes
    k_hop<<<hop_blocks, 256, 0, stream>>>(rp2, csr, dinv2, xb, h1b);   // -> y1
    k_hop<<<hop_blocks, 256, 0, stream>>>(rp2, csr, dinv, h1b, h2b);   // -> h2

    k_gemm_lsm_mfma<<<512, 256, 0, stream>>>((const unsigned short*)(h2b + 32), W, b, out);
}